// Round 12
// baseline (1163.177 us; speedup 1.0000x reference)
//
#include <hip/hip_runtime.h>

// Problem constants (from reference)
constexpr int B_ = 8;
constexpr int N_ = 16384;
constexpr int NG = 512;     // NUM_GROUPS
constexpr int GS = 32;      // GROUP_SIZE
constexpr int KORIG = 160;  // K_ORIGINAL = 5*GROUP_SIZE
constexpr int TPB = 256;    // fps threads: 4 waves, 1 per SIMD
constexpr int PPT = 64;     // points per thread (32 pk pairs), contiguous
#define R2 0.04f
#define RADIUS 0.2f

typedef __attribute__((ext_vector_type(2))) float f32x2;
typedef __attribute__((ext_vector_type(4))) float f32x4;

__device__ __forceinline__ unsigned f32_ord(float f) {
  unsigned u = __float_as_uint(f);
  return (u & 0x80000000u) ? ~u : (u | 0x80000000u);
}

// packed f32 math: IEEE-identical per component to scalar v_add/v_mul
__device__ __forceinline__ f32x2 pk_add(f32x2 a, f32x2 b) {
  f32x2 d;
  asm("v_pk_add_f32 %0, %1, %2" : "=v"(d) : "v"(a), "v"(b));
  return d;
}
__device__ __forceinline__ f32x2 pk_mul(f32x2 a, f32x2 b) {
  f32x2 d;
  asm("v_pk_mul_f32 %0, %1, %2" : "=v"(d) : "v"(a), "v"(b));
  return d;
}

template <int CTRL>
__device__ __forceinline__ float dpp_fmax(float v) {
  int o = __builtin_amdgcn_update_dpp(0, __float_as_int(v), CTRL, 0xF, 0xF, true);
  return fmaxf(v, __int_as_float(o));
}
template <int CTRL>
__device__ __forceinline__ unsigned dpp_umax(unsigned v) {
  int o = __builtin_amdgcn_update_dpp(0, (int)v, CTRL, 0xF, 0xF, true);
  return v > (unsigned)o ? v : (unsigned)o;
}
// full 64-lane max
__device__ __forceinline__ float wave_fmax(float v) {
  v = dpp_fmax<0xB1>(v);   // quad_perm xor1
  v = dpp_fmax<0x4E>(v);   // quad_perm xor2
  v = dpp_fmax<0x141>(v);  // row_half_mirror
  v = dpp_fmax<0x140>(v);  // row_mirror
  v = fmaxf(v, __int_as_float(__builtin_amdgcn_ds_swizzle(__float_as_int(v), 0x401F)));  // xor16
  v = fmaxf(v, __shfl_xor(v, 32, 64));  // xor32
  return v;
}

// ---------------- Kernel 1: farthest point sampling ----------------
// One block per batch, 256 threads (4 waves, 1/SIMD); thread t owns points
// [64t, 64t+64) CONTIGUOUS (tie-break = wave, lane, j = original index order).
// BARRIER-FREE main loop (r11 post-mortem: the 16-wave s_barrier ~1400cy was
// the invariant per-iteration wall): waves sync via tagged LDS slots +
// acquire-poll; parity double-buffer; 2-step quad-DPP cross-wave reduce;
// winner coords via wave-uniform s_load. 128KiB LDS pins occupancy to
// 1 wave/SIMD -> allocator has no reason to spill m2/z2 (128 VGPRs live).
__global__ __attribute__((amdgpu_flat_work_group_size(256, 256),
                          amdgpu_waves_per_eu(1, 1)))
void fps_kernel(const float4* __restrict__ p4,
                const int* __restrict__ lengths,
                float* __restrict__ centers) {
#pragma clang fp contract(off)
  const int b = blockIdx.x;
  const int t = threadIdx.x;
  const int lane = t & 63;
  const int wid = t >> 6;
  const int len = lengths[b];
  const float4* bp = p4 + (size_t)b * N_;
  const float INF = __builtin_inff();

  __shared__ f32x4 sxy4[32 * 4 * 64];          // 128 KiB: [(wid*32+p)*64+lane]
  __shared__ unsigned long long pub[2][4];     // ord(wmax)<<32 | k<<14 | gidx

  const int base4 = wid * 2048 + lane;  // + p*64

  f32x2 z2[32], m2[32];
#pragma unroll
  for (int p = 0; p < 32; ++p) {
    const int i0 = t * PPT + 2 * p;
    float4 a = bp[i0];
    float4 c = bp[i0 + 1];
    sxy4[base4 + p * 64] = (f32x4){a.x, c.x, a.y, c.y};
    z2[p] = (f32x2){a.z, c.z};
    m2[p].x = (i0 < len) ? INF : -INF;
    m2[p].y = (i0 + 1 < len) ? INF : -INF;
  }
  if (t < 8) ((unsigned long long*)pub)[t] = ~0ull;  // stale-tag proof
  __syncthreads();  // one-time: LDS xy + pub init visible to all waves

  float4 c0 = bp[0];  // reference scan starts at cur=0
  float cx = c0.x, cy = c0.y, cz = c0.z;
  if (t == 0) {
    size_t o = (size_t)b * NG * 3;
    centers[o] = cx; centers[o + 1] = cy; centers[o + 2] = cz;
  }

  for (int k = 0; k < NG - 1; ++k) {
    // --- mindist update: pk math, 2 points/instr, exact reference rounding ---
    const f32x2 mcx = {-cx, -cx};
    const f32x2 mcy = {-cy, -cy};
    const f32x2 mcz = {-cz, -cz};
#pragma unroll
    for (int p = 0; p < 32; ++p) {
      f32x4 q = sxy4[base4 + p * 64];   // (xA,xB,yA,yB), static-offset b128
      f32x2 xx = pk_add(q.xy, mcx);     // x - cx (as x + (-cx), exact)
      f32x2 yy = pk_add(q.zw, mcy);
      f32x2 zz = pk_add(z2[p], mcz);
      f32x2 x2 = pk_mul(xx, xx);
      f32x2 y2 = pk_mul(yy, yy);
      f32x2 s1 = pk_add(x2, y2);        // dx2 + dy2
      f32x2 zq = pk_mul(zz, zz);
      f32x2 d2 = pk_add(s1, zq);        // (dx2+dy2) + dz2 = np.sum order
      m2[p].x = fminf(m2[p].x, d2.x);
      m2[p].y = fminf(m2[p].y, d2.y);
    }
    // --- max tree over 32 pair-maxes (levels kept for descent) ---
    float a32[32];
#pragma unroll
    for (int i = 0; i < 32; ++i) a32[i] = fmaxf(m2[i].x, m2[i].y);
    float a16[16];
#pragma unroll
    for (int i = 0; i < 16; ++i) a16[i] = fmaxf(a32[2 * i], a32[2 * i + 1]);
    float a8[8];
#pragma unroll
    for (int i = 0; i < 8; ++i) a8[i] = fmaxf(a16[2 * i], a16[2 * i + 1]);
    float a4[4];
#pragma unroll
    for (int i = 0; i < 4; ++i) a4[i] = fmaxf(a8[2 * i], a8[2 * i + 1]);
    float a2[2] = {fmaxf(a4[0], a4[1]), fmaxf(a4[2], a4[3])};
    const float sm = fmaxf(a2[0], a2[1]);

    // --- leftmost-attaining leaf via 5-level descent (static selects only) ---
    const bool i1 = (a2[0] != sm);
    const float aL4 = i1 ? a4[2] : a4[0];
    const bool i2 = (aL4 != sm);
    const float aL8 = i1 ? (i2 ? a8[6] : a8[4]) : (i2 ? a8[2] : a8[0]);
    const bool i3 = (aL8 != sm);
    const float aL16 = i1 ? (i2 ? (i3 ? a16[14] : a16[12]) : (i3 ? a16[10] : a16[8]))
                          : (i2 ? (i3 ? a16[6] : a16[4]) : (i3 ? a16[2] : a16[0]));
    const bool i4 = (aL16 != sm);
    const float aL32 =
        i1 ? (i2 ? (i3 ? (i4 ? a32[30] : a32[28]) : (i4 ? a32[26] : a32[24]))
                 : (i3 ? (i4 ? a32[22] : a32[20]) : (i4 ? a32[18] : a32[16])))
           : (i2 ? (i3 ? (i4 ? a32[14] : a32[12]) : (i4 ? a32[10] : a32[8]))
                 : (i3 ? (i4 ? a32[6] : a32[4]) : (i4 ? a32[2] : a32[0])));
    const bool i5 = (aL32 != sm);
    const int jp = ((int)i1 << 4) | ((int)i2 << 3) | ((int)i3 << 2) |
                   ((int)i4 << 1) | (int)i5;
    const float mlo =
        i1 ? (i2 ? (i3 ? (i4 ? (i5 ? m2[31].x : m2[30].x) : (i5 ? m2[29].x : m2[28].x))
                       : (i4 ? (i5 ? m2[27].x : m2[26].x) : (i5 ? m2[25].x : m2[24].x)))
                 : (i3 ? (i4 ? (i5 ? m2[23].x : m2[22].x) : (i5 ? m2[21].x : m2[20].x))
                       : (i4 ? (i5 ? m2[19].x : m2[18].x) : (i5 ? m2[17].x : m2[16].x))))
           : (i2 ? (i3 ? (i4 ? (i5 ? m2[15].x : m2[14].x) : (i5 ? m2[13].x : m2[12].x))
                       : (i4 ? (i5 ? m2[11].x : m2[10].x) : (i5 ? m2[9].x : m2[8].x)))
                 : (i3 ? (i4 ? (i5 ? m2[7].x : m2[6].x) : (i5 ? m2[5].x : m2[4].x))
                       : (i4 ? (i5 ? m2[3].x : m2[2].x) : (i5 ? m2[1].x : m2[0].x))));
    const bool blo = (mlo != sm);  // false -> low half attains (first index)
    const int gidx = t * PPT + jp * 2 + (int)blo;

    // --- wave max + first-lane tie-break ---
    const float wmax = wave_fmax(sm);
    const unsigned long long att = __ballot(sm == wmax);
    const int wl = __ffsll(att) - 1;  // lowest lane = lowest index

    // --- tagged publish (no barrier) ---
    if (lane == wl) {
      unsigned long long val = ((unsigned long long)f32_ord(wmax) << 32) |
                               (unsigned)((k << 14) | gidx);
      __hip_atomic_store(&pub[k & 1][wid], val, __ATOMIC_RELEASE,
                         __HIP_MEMORY_SCOPE_WORKGROUP);
    }
    // --- acquire-poll the 4 slots until all carry tag k ---
    unsigned long long pv = 0;
    const bool po = lane < 4;
    for (;;) {
      if (po) pv = __hip_atomic_load(&pub[k & 1][lane], __ATOMIC_ACQUIRE,
                                     __HIP_MEMORY_SCOPE_WORKGROUP);
      const bool ok = !po || (((unsigned)pv >> 14) == (unsigned)k);
      if (__all(ok)) break;
    }
    // --- cross-wave reduce: quad-DPP u32 max, lowest wave wins ties ---
    const unsigned o0 = po ? (unsigned)(pv >> 32) : 0u;
    unsigned km = dpp_umax<0xB1>(o0);
    km = dpp_umax<0x4E>(km);               // lanes 0-3 now hold quad max
    const unsigned long long bal = __ballot(po && (o0 == km)) & 0xFull;
    const int src = __ffsll(bal) - 1;      // lowest wid = lowest index
    const int gsel = __shfl((int)((unsigned)pv & 0x3FFFu), src, 64);
    const int snxt = __builtin_amdgcn_readfirstlane(gsel);
    const float4 c = bp[snxt];             // wave-uniform s_load, L2-hot
    cx = c.x; cy = c.y; cz = c.z;

    if (t == 0) {
      size_t o = ((size_t)b * NG + (k + 1)) * 3;
      centers[o] = cx; centers[o + 1] = cy; centers[o + 2] = cz;
    }
  }
}

// ---------------- Kernel 2: ball query + energy top-k + gather ----------------
// One wave per (batch, group). Ordered compaction of first 160 in-ball indices,
// then 32 rounds of min-key extraction = top_k by (energy desc, index asc).
__global__ __launch_bounds__(64) void group_kernel(const float4* __restrict__ p4,
                                                   const int* __restrict__ lengths,
                                                   const float* __restrict__ centers,
                                                   float4* __restrict__ outg) {
#pragma clang fp contract(off)
  const int gid = blockIdx.x;
  const int b = gid >> 9;
  const int lane = threadIdx.x;
  const int len = lengths[b];
  const float4* bp = p4 + (size_t)b * N_;
  const float cx = centers[(size_t)gid * 3 + 0];
  const float cy = centers[(size_t)gid * 3 + 1];
  const float cz = centers[(size_t)gid * 3 + 2];

  __shared__ int cand[KORIG];
  int M = 0;  // wave-uniform running in-ball count
  for (int cb = 0; cb < N_ && M < KORIG; cb += 256) {
#pragma unroll
    for (int q = 0; q < 4; ++q) {
      const int i = cb + q * 64 + lane;
      float4 p = bp[i];
      float dx = p.x - cx;
      float dy = p.y - cy;
      float dz = p.z - cz;
      float d2 = dx * dx + dy * dy + dz * dz;  // contract OFF
      const bool pred = (i < len) && (d2 < R2);
      unsigned long long mb = __ballot(pred);
      if (pred) {
        int pos = M + (int)__popcll(mb & ((1ull << lane) - 1ull));
        if (pos < KORIG) cand[pos] = i;  // first-160-by-index semantics
      }
      M += (int)__popcll(mb);
    }
  }
  if (M > KORIG) M = KORIG;
  __syncthreads();

  // keys: (energy desc, index asc) -> ascending u64
  const unsigned long long SENT = ~0ull;
  unsigned long long key0 = SENT, key1 = SENT, key2 = SENT;
  {
    int c0 = lane, c1 = lane + 64, c2 = lane + 128;
    if (c0 < M) { int i = cand[c0]; key0 = ((unsigned long long)(~f32_ord(bp[i].w)) << 32) | (unsigned)i; }
    if (c1 < M) { int i = cand[c1]; key1 = ((unsigned long long)(~f32_ord(bp[i].w)) << 32) | (unsigned)i; }
    if (c2 < M) { int i = cand[c2]; key2 = ((unsigned long long)(~f32_ord(bp[i].w)) << 32) | (unsigned)i; }
  }

  int mysel = -1;  // lane j holds the j-th selected index
  for (int j = 0; j < GS; ++j) {
    unsigned long long kmin = key0 < key1 ? key0 : key1;
    if (key2 < kmin) kmin = key2;
#pragma unroll
    for (int off = 32; off > 0; off >>= 1) {
      unsigned long long o = __shfl_xor(kmin, off, 64);
      if (o < kmin) kmin = o;
    }
    if (kmin == SENT) break;  // fewer than 32 candidates; rest stay -1
    if (lane == j) mysel = (int)(unsigned)kmin;
    if (key0 == kmin) key0 = SENT;
    if (key1 == kmin) key1 = SENT;
    if (key2 == kmin) key2 = SENT;
  }

  const int first = __shfl(mysel, 0, 64);  // highest-energy candidate (or -1 if empty)
  if (lane < GS) {
    int idx = (mysel < 0) ? first : mysel;  // reference: -1 -> idx[:, :, :1]
    float4 o;
    if (idx >= 0) {
      float4 p = bp[idx];
      o.x = (p.x - cx) / RADIUS;
      o.y = (p.y - cy) / RADIUS;
      o.z = (p.z - cz) / RADIUS;
      o.w = p.w / RADIUS;
    } else {
      // masked_gather gives 0, then (0 - center)/radius
      o.x = (0.0f - cx) / RADIUS;
      o.y = (0.0f - cy) / RADIUS;
      o.z = (0.0f - cz) / RADIUS;
      o.w = 0.0f;
    }
    outg[(size_t)gid * GS + lane] = o;
  }
}

extern "C" void kernel_launch(void* const* d_in, const int* in_sizes, int n_in,
                              void* d_out, int out_size, void* d_ws, size_t ws_size,
                              hipStream_t stream) {
  const float4* pts = (const float4*)d_in[0];
  const int* lengths = (const int*)d_in[1];
  float* out = (float*)d_out;
  // out layout: groups (8,512,32,4) flat, then centers (8,512,3) flat
  float* centers = out + (size_t)B_ * NG * GS * 4;
  float4* groups = (float4*)out;

  fps_kernel<<<B_, TPB, 0, stream>>>(pts, lengths, centers);
  group_kernel<<<B_ * NG, 64, 0, stream>>>(pts, lengths, centers, groups);
}

// Round 13
// 891.426 us; speedup vs baseline: 1.3048x; 1.3048x over previous
//
#include <hip/hip_runtime.h>

// Problem constants (from reference)
constexpr int B_ = 8;
constexpr int N_ = 16384;
constexpr int NG = 512;     // NUM_GROUPS
constexpr int GS = 32;      // GROUP_SIZE
constexpr int KORIG = 160;  // K_ORIGINAL = 5*GROUP_SIZE
constexpr int TPB = 512;    // fps threads: 8 waves, 2 per SIMD
constexpr int PPT = 32;     // points per thread (16 pk pairs), contiguous
#define R2 0.04f
#define RADIUS 0.2f

typedef __attribute__((ext_vector_type(2))) float f32x2;

__device__ __forceinline__ unsigned f32_ord(float f) {
  unsigned u = __float_as_uint(f);
  return (u & 0x80000000u) ? ~u : (u | 0x80000000u);
}

// packed f32 math: IEEE-identical per component to scalar v_add/v_mul
__device__ __forceinline__ f32x2 pk_add(f32x2 a, f32x2 b) {
  f32x2 d;
  asm("v_pk_add_f32 %0, %1, %2" : "=v"(d) : "v"(a), "v"(b));
  return d;
}
__device__ __forceinline__ f32x2 pk_mul(f32x2 a, f32x2 b) {
  f32x2 d;
  asm("v_pk_mul_f32 %0, %1, %2" : "=v"(d) : "v"(a), "v"(b));
  return d;
}

template <int CTRL>
__device__ __forceinline__ float dpp_fmax(float v) {
  int o = __builtin_amdgcn_update_dpp(0, __float_as_int(v), CTRL, 0xF, 0xF, true);
  return fmaxf(v, __int_as_float(o));
}
// full 64-lane max
__device__ __forceinline__ float wave_fmax(float v) {
  v = dpp_fmax<0xB1>(v);   // quad_perm xor1
  v = dpp_fmax<0x4E>(v);   // quad_perm xor2
  v = dpp_fmax<0x141>(v);  // row_half_mirror
  v = dpp_fmax<0x140>(v);  // row_mirror
  v = fmaxf(v, __int_as_float(__builtin_amdgcn_ds_swizzle(__float_as_int(v), 0x401F)));  // xor16
  v = fmaxf(v, __shfl_xor(v, 32, 64));  // xor32
  return v;
}
// max within each 8-lane group (lanes 8g..8g+7 hold the 8 wave partials)
__device__ __forceinline__ float group8_fmax(float v) {
  v = dpp_fmax<0xB1>(v);
  v = dpp_fmax<0x4E>(v);
  v = dpp_fmax<0x141>(v);
  return v;
}

// ---------------- Kernel 1: farthest point sampling ----------------
// One block per batch, 512 threads (8 waves, 2/SIMD); thread t owns points
// [32t,32t+32) CONTIGUOUS (tie-break = wave, lane, j = original index order).
// ZERO-LDS main loop (r8-r12 post-mortem: the invariant ~1.7us/iter tracked
// the 128KiB/iter LDS xy re-read, not VALU/barrier/global ops): x,y,z,m all
// live in registers as f32x2 arrays (128 persistent VGPRs);
// amdgpu_waves_per_eu(2,2) forces the allocator to use the 256-reg budget
// (r12 proved the attribute form works where launch_bounds didn't).
// Single barrier per iteration, parity publish, r9-validated reduce flow.
__global__ __attribute__((amdgpu_flat_work_group_size(512, 512),
                          amdgpu_waves_per_eu(2, 2)))
void fps_kernel(const float4* __restrict__ p4,
                const int* __restrict__ lengths,
                float* __restrict__ centers) {
#pragma clang fp contract(off)
  const int b = blockIdx.x;
  const int t = threadIdx.x;
  const int lane = t & 63;
  const int wid = t >> 6;
  const int len = lengths[b];
  const float4* bp = p4 + (size_t)b * N_;
  const float INF = __builtin_inff();

  __shared__ float pubf[2][8];  // per-wave max, parity dbuf
  __shared__ int pubi[2][8];    // per-wave winner global index, parity dbuf

  f32x2 x2[16], y2[16], z2[16], m2[16];
#pragma unroll
  for (int p = 0; p < 16; ++p) {
    const int i0 = t * PPT + 2 * p;
    float4 a = bp[i0];       // per-thread contiguous 512B: full line use
    float4 c = bp[i0 + 1];
    x2[p] = (f32x2){a.x, c.x};
    y2[p] = (f32x2){a.y, c.y};
    z2[p] = (f32x2){a.z, c.z};
    m2[p].x = (i0 < len) ? INF : -INF;
    m2[p].y = (i0 + 1 < len) ? INF : -INF;
  }

  float4 c0 = bp[0];  // reference scan starts at cur=0
  float cx = c0.x, cy = c0.y, cz = c0.z;
  if (t == 0) {
    size_t o = (size_t)b * NG * 3;
    centers[o] = cx; centers[o + 1] = cy; centers[o + 2] = cz;
  }

  for (int k = 0; k < NG - 1; ++k) {
    // --- mindist update: all-register pk math, exact reference rounding ---
    const f32x2 mcx = {-cx, -cx};
    const f32x2 mcy = {-cy, -cy};
    const f32x2 mcz = {-cz, -cz};
#pragma unroll
    for (int p = 0; p < 16; ++p) {
      f32x2 xx = pk_add(x2[p], mcx);   // x - cx (as x + (-cx), exact)
      f32x2 yy = pk_add(y2[p], mcy);
      f32x2 zz = pk_add(z2[p], mcz);
      f32x2 xs = pk_mul(xx, xx);
      f32x2 ys = pk_mul(yy, yy);
      f32x2 s1 = pk_add(xs, ys);       // dx2 + dy2
      f32x2 zs = pk_mul(zz, zz);
      f32x2 d2 = pk_add(s1, zs);       // (dx2+dy2) + dz2 = np.sum order
      m2[p].x = fminf(m2[p].x, d2.x);
      m2[p].y = fminf(m2[p].y, d2.y);
    }
    // --- thread max tree over 16 pair-maxes (levels kept for descent) ---
    float pm[16];
#pragma unroll
    for (int i = 0; i < 16; ++i) pm[i] = fmaxf(m2[i].x, m2[i].y);
    float b8[8];
#pragma unroll
    for (int i = 0; i < 8; ++i) b8[i] = fmaxf(pm[2 * i], pm[2 * i + 1]);
    float b4[4];
#pragma unroll
    for (int i = 0; i < 4; ++i) b4[i] = fmaxf(b8[2 * i], b8[2 * i + 1]);
    float b2[2] = {fmaxf(b4[0], b4[1]), fmaxf(b4[2], b4[3])};
    const float sm = fmaxf(b2[0], b2[1]);

    // --- leftmost-attaining leaf via 4-level descent + pair bit ---
    const bool i1 = (b2[0] != sm);
    const float aL4 = i1 ? b4[2] : b4[0];
    const bool i2 = (aL4 != sm);
    const float aL8 = i1 ? (i2 ? b8[6] : b8[4]) : (i2 ? b8[2] : b8[0]);
    const bool i3 = (aL8 != sm);
    const float pmL = i1 ? (i2 ? (i3 ? pm[14] : pm[12]) : (i3 ? pm[10] : pm[8]))
                         : (i2 ? (i3 ? pm[6] : pm[4]) : (i3 ? pm[2] : pm[0]));
    const bool i4 = (pmL != sm);
    const int jp = ((int)i1 << 3) | ((int)i2 << 2) | ((int)i3 << 1) | (int)i4;
    const float mlo =
        i1 ? (i2 ? (i3 ? (i4 ? m2[15].x : m2[14].x) : (i4 ? m2[13].x : m2[12].x))
                 : (i3 ? (i4 ? m2[11].x : m2[10].x) : (i4 ? m2[9].x : m2[8].x)))
           : (i2 ? (i3 ? (i4 ? m2[7].x : m2[6].x) : (i4 ? m2[5].x : m2[4].x))
                 : (i3 ? (i4 ? m2[3].x : m2[2].x) : (i4 ? m2[1].x : m2[0].x)));
    const bool blo = (mlo != sm);  // false -> low half attains (first index)
    const int gidx = t * PPT + jp * 2 + (int)blo;

    // --- wave max + first-lane tie-break; publish (value, index) ---
    const float wmax = wave_fmax(sm);
    const unsigned long long att = __ballot(sm == wmax);
    const int wl = __ffsll(att) - 1;  // lowest lane = lowest index
    if (lane == wl) {
      pubf[k & 1][wid] = wmax;
      pubi[k & 1][wid] = gidx;
    }
    __syncthreads();  // the only barrier; parity slots make one enough

    // --- all waves: read 8 partials, reduce, broadcast, s_load winner ---
    const float pw = pubf[k & 1][lane & 7];
    const int pi = pubi[k & 1][lane & 7];
    const float kmax = group8_fmax(pw);
    const unsigned long long bal = __ballot(pw == kmax);
    const int grp = lane & 56;
    const int src = grp + (__ffsll((bal >> grp) & 0xFFull) - 1);  // lowest wave wins
    const int gsel = __shfl(pi, src, 64);
    const int snxt = __builtin_amdgcn_readfirstlane(gsel);  // SGPR -> s_load
    const float4 c = bp[snxt];                              // wave-uniform, L2-hot
    cx = c.x; cy = c.y; cz = c.z;

    if (t == 0) {
      size_t o = ((size_t)b * NG + (k + 1)) * 3;
      centers[o] = cx; centers[o + 1] = cy; centers[o + 2] = cz;
    }
  }
}

// ---------------- Kernel 2: ball query + energy top-k + gather ----------------
// One wave per (batch, group). Ordered compaction of first 160 in-ball indices,
// then 32 rounds of min-key extraction = top_k by (energy desc, index asc).
__global__ __launch_bounds__(64) void group_kernel(const float4* __restrict__ p4,
                                                   const int* __restrict__ lengths,
                                                   const float* __restrict__ centers,
                                                   float4* __restrict__ outg) {
#pragma clang fp contract(off)
  const int gid = blockIdx.x;
  const int b = gid >> 9;
  const int lane = threadIdx.x;
  const int len = lengths[b];
  const float4* bp = p4 + (size_t)b * N_;
  const float cx = centers[(size_t)gid * 3 + 0];
  const float cy = centers[(size_t)gid * 3 + 1];
  const float cz = centers[(size_t)gid * 3 + 2];

  __shared__ int cand[KORIG];
  int M = 0;  // wave-uniform running in-ball count
  for (int cb = 0; cb < N_ && M < KORIG; cb += 256) {
#pragma unroll
    for (int q = 0; q < 4; ++q) {
      const int i = cb + q * 64 + lane;
      float4 p = bp[i];
      float dx = p.x - cx;
      float dy = p.y - cy;
      float dz = p.z - cz;
      float d2 = dx * dx + dy * dy + dz * dz;  // contract OFF
      const bool pred = (i < len) && (d2 < R2);
      unsigned long long mb = __ballot(pred);
      if (pred) {
        int pos = M + (int)__popcll(mb & ((1ull << lane) - 1ull));
        if (pos < KORIG) cand[pos] = i;  // first-160-by-index semantics
      }
      M += (int)__popcll(mb);
    }
  }
  if (M > KORIG) M = KORIG;
  __syncthreads();

  // keys: (energy desc, index asc) -> ascending u64
  const unsigned long long SENT = ~0ull;
  unsigned long long key0 = SENT, key1 = SENT, key2 = SENT;
  {
    int c0 = lane, c1 = lane + 64, c2 = lane + 128;
    if (c0 < M) { int i = cand[c0]; key0 = ((unsigned long long)(~f32_ord(bp[i].w)) << 32) | (unsigned)i; }
    if (c1 < M) { int i = cand[c1]; key1 = ((unsigned long long)(~f32_ord(bp[i].w)) << 32) | (unsigned)i; }
    if (c2 < M) { int i = cand[c2]; key2 = ((unsigned long long)(~f32_ord(bp[i].w)) << 32) | (unsigned)i; }
  }

  int mysel = -1;  // lane j holds the j-th selected index
  for (int j = 0; j < GS; ++j) {
    unsigned long long kmin = key0 < key1 ? key0 : key1;
    if (key2 < kmin) kmin = key2;
#pragma unroll
    for (int off = 32; off > 0; off >>= 1) {
      unsigned long long o = __shfl_xor(kmin, off, 64);
      if (o < kmin) kmin = o;
    }
    if (kmin == SENT) break;  // fewer than 32 candidates; rest stay -1
    if (lane == j) mysel = (int)(unsigned)kmin;
    if (key0 == kmin) key0 = SENT;
    if (key1 == kmin) key1 = SENT;
    if (key2 == kmin) key2 = SENT;
  }

  const int first = __shfl(mysel, 0, 64);  // highest-energy candidate (or -1 if empty)
  if (lane < GS) {
    int idx = (mysel < 0) ? first : mysel;  // reference: -1 -> idx[:, :, :1]
    float4 o;
    if (idx >= 0) {
      float4 p = bp[idx];
      o.x = (p.x - cx) / RADIUS;
      o.y = (p.y - cy) / RADIUS;
      o.z = (p.z - cz) / RADIUS;
      o.w = p.w / RADIUS;
    } else {
      // masked_gather gives 0, then (0 - center)/radius
      o.x = (0.0f - cx) / RADIUS;
      o.y = (0.0f - cy) / RADIUS;
      o.z = (0.0f - cz) / RADIUS;
      o.w = 0.0f;
    }
    outg[(size_t)gid * GS + lane] = o;
  }
}

extern "C" void kernel_launch(void* const* d_in, const int* in_sizes, int n_in,
                              void* d_out, int out_size, void* d_ws, size_t ws_size,
                              hipStream_t stream) {
  const float4* pts = (const float4*)d_in[0];
  const int* lengths = (const int*)d_in[1];
  float* out = (float*)d_out;
  // out layout: groups (8,512,32,4) flat, then centers (8,512,3) flat
  float* centers = out + (size_t)B_ * NG * GS * 4;
  float4* groups = (float4*)out;

  fps_kernel<<<B_, TPB, 0, stream>>>(pts, lengths, centers);
  group_kernel<<<B_ * NG, 64, 0, stream>>>(pts, lengths, centers, groups);
}